// Round 8
// baseline (331.040 us; speedup 1.0000x reference)
//
#include <hip/hip_runtime.h>
#include <stdint.h>

// MultiBoxLoss: B=64 rows, D=65536 anchors, ~2% positives.
// R8: single fused kernel (1024 blocks) + 1KB memset. R7 still serialized
// k1 -> ksel -> k5 across launches (ksel's ~20us latency fully exposed).
// Phase A streams conf/conft + compacts candidates to a contiguous per-row
// buffer; the LAST block of each row (device-scope atomic) runs the per-row
// top-k select immediately, overlapped with other rows' streaming; the last
// of the 64 selectors runs the final combine. Fences + device atomics per
// G16 (XCD-safe, no dispatch-order assumptions, no spinning).

#define B_ 64
#define D_ 65536
#define NEGPOS 3
#define BPR 16                 // blocks per row
#define NBLK (B_ * BPR)        // 1024
#define CHUNK (D_ / BPR)       // 4096 elements per block
#define XC 1.25f               // candidate cutoff (~10.6% of negatives)
#define CAPR 16384             // per-row candidate capacity (expect ~6.9k, 22 sigma)
#define HBINS 4096             // select histogram bins over x in [XC, XC+XRANGE)
#define XRANGE 5.0f
#define CJCAP 1024             // k-th-bin gather capacity (expect ~8)

// ---------------- ws layout (bytes) ----------------
// zeroed by the 1KB memset:
#define OFF_CANDCNT  0                      // u32[64]
#define OFF_NPROW    256                    // u32[64]
#define OFF_ROWDONE  512                    // u32[64]
#define OFF_ALLDONE  768                    // u32
#define ZERO_BYTES   1024
// not zeroed (written unconditionally every call):
#define OFF_SL1P     1024                   // double[NBLK]
#define OFF_BCEP     9216                   // double[NBLK]
#define OFF_NEGSUM   17408                  // double[64]
#define OFF_KSEL     17920                  // int[64]
#define OFF_CAND     32768                  // float[64][CAPR] = 4 MiB

__device__ __forceinline__ float softplus_f(float x) {   // bce for t=0
    return fmaxf(x, 0.0f) + log1pf(expf(-fabsf(x)));
}

__device__ __forceinline__ int bin_of_x(float x) {
    int b = (int)((x - XC) * ((float)HBINS / XRANGE));
    return max(0, min(HBINS - 1, b));
}

__device__ __forceinline__ unsigned sortkey(float x) {
    unsigned u = __float_as_uint(x);
    return (u & 0x80000000u) ? ~u : (u | 0x80000000u);
}
__device__ __forceinline__ float unsortkey(unsigned s) {
    unsigned u = (s & 0x80000000u) ? (s & 0x7FFFFFFFu) : ~s;
    return __uint_as_float(u);
}

__device__ __forceinline__ float smooth_l1_4(float4 a, float4 b) {
    float s = 0.0f, d, ad;
    d = a.x - b.x; ad = fabsf(d); s += (ad < 1.0f) ? 0.5f * d * d : ad - 0.5f;
    d = a.y - b.y; ad = fabsf(d); s += (ad < 1.0f) ? 0.5f * d * d : ad - 0.5f;
    d = a.z - b.z; ad = fabsf(d); s += (ad < 1.0f) ? 0.5f * d * d : ad - 0.5f;
    d = a.w - b.w; ad = fabsf(d); s += (ad < 1.0f) ? 0.5f * d * d : ad - 0.5f;
    return s;
}

__device__ __forceinline__ double wredD(double v) {
#pragma unroll
    for (int o = 32; o > 0; o >>= 1) v += __shfl_down(v, o, 64);
    return v;
}
__device__ __forceinline__ int wredI(int v) {
#pragma unroll
    for (int o = 32; o > 0; o >>= 1) v += __shfl_down(v, o, 64);
    return v;
}

union ShUnion {
    struct { float lcand[CHUNK]; unsigned short lpos[CHUNK]; } a;  // phase A: 24 KB
    struct { unsigned hist[HBINS]; unsigned ubuf[CJCAP]; } b;      // phase B: 20 KB
};

__global__ void __launch_bounds__(256)
mbl_fused(const float4* __restrict__ loc4, const float* __restrict__ conf,
          const float4* __restrict__ loct4, const int* __restrict__ conft,
          unsigned char* __restrict__ ws, float* __restrict__ out)
{
    __shared__ ShUnion sh;
    __shared__ unsigned wtot[4], wsuf[4];
    __shared__ unsigned shSel, shBase, shJ, shRemJ, shCj, shWin;
    __shared__ float shXT;
    __shared__ int shI[4], shN[4], shK[4];
    __shared__ double wr[8], wrC[4];

    const int block = blockIdx.x;
    const int row = block / BPR;
    const int base = block * CHUNK;
    const int lane = threadIdx.x & 63, wid = threadIdx.x >> 6;
    const int tid = threadIdx.x;

    unsigned* candcnt = (unsigned*)(ws + OFF_CANDCNT);
    unsigned* nprow   = (unsigned*)(ws + OFF_NPROW);
    unsigned* rowdone = (unsigned*)(ws + OFF_ROWDONE);
    unsigned* alldone = (unsigned*)(ws + OFF_ALLDONE);
    double*   sl1p    = (double*)(ws + OFF_SL1P);
    double*   bcepp   = (double*)(ws + OFF_BCEP);
    double*   negsum  = (double*)(ws + OFF_NEGSUM);
    int*      kselp   = (int*)(ws + OFF_KSEL);
    float*    cand    = (float*)(ws + OFF_CAND);

    // ================= PHASE A: stream conf/conft =================
    {
        const float4* c4 = (const float4*)(conf + base);
        const int4*   t4 = (const int4*)(conft + base);
        float4 xv[4]; int4 tv[4];
#pragma unroll
        for (int it = 0; it < 4; it++) {
            const int g = tid + it * 256;
            xv[it] = c4[g];
            tv[it] = t4[g];
        }

        double bcep = 0.0;
        unsigned cntc = 0, cntp = 0;
#pragma unroll
        for (int it = 0; it < 4; it++) {
#pragma unroll
            for (int c = 0; c < 4; c++) {
                float x = (c == 0) ? xv[it].x : (c == 1) ? xv[it].y : (c == 2) ? xv[it].z : xv[it].w;
                int   t = (c == 0) ? tv[it].x : (c == 1) ? tv[it].y : (c == 2) ? tv[it].z : tv[it].w;
                if (t > 0) { cntp++; bcep += (double)(softplus_f(x) - x); }
                else if (x >= XC) cntc++;
            }
        }

        unsigned pk = (cntc << 16) | cntp;
        unsigned incl = pk;
#pragma unroll
        for (int o = 1; o < 64; o <<= 1) {
            unsigned v = __shfl_up(incl, o, 64);
            if (lane >= o) incl += v;
        }
        unsigned excl = incl - pk;
        if (lane == 63) wtot[wid] = incl;
        __syncthreads();
        unsigned wbase = 0;
        for (int w = 0; w < wid; w++) wbase += wtot[w];
        const unsigned tot = wtot[0] + wtot[1] + wtot[2] + wtot[3];
        const unsigned totc = tot >> 16, totp = tot & 0xFFFFu;
        unsigned offc = (excl >> 16) + (wbase >> 16);
        unsigned offp = (excl & 0xFFFFu) + (wbase & 0xFFFFu);

#pragma unroll
        for (int it = 0; it < 4; it++) {
#pragma unroll
            for (int c = 0; c < 4; c++) {
                float x = (c == 0) ? xv[it].x : (c == 1) ? xv[it].y : (c == 2) ? xv[it].z : xv[it].w;
                int   t = (c == 0) ? tv[it].x : (c == 1) ? tv[it].y : (c == 2) ? tv[it].z : tv[it].w;
                const int li = (tid + it * 256) * 4 + c;
                if (t > 0) sh.a.lpos[offp++] = (unsigned short)li;
                else if (x >= XC) sh.a.lcand[offc++] = x;
            }
        }
        __syncthreads();

        if (tid == 0) {
            shBase = atomicAdd(&candcnt[row], totc);
            if (totp) atomicAdd(&nprow[row], totp);
        }
        __syncthreads();
        {
            float* crow = cand + (size_t)row * CAPR;
            const unsigned b0 = shBase;
            for (unsigned i = tid; i < totc; i += 256) {
                unsigned p = b0 + i;
                if (p < CAPR) crow[p] = sh.a.lcand[i];   // overflow -> fb path
            }
        }

        double sl1 = 0.0;
        for (unsigned i = tid; i < totp; i += 256) {
            const int e = base + (int)sh.a.lpos[i];
            sl1 += (double)smooth_l1_4(loc4[e], loct4[e]);
        }

        double s1 = wredD(sl1), s2 = wredD(bcep);
        if (lane == 0) { wr[wid] = s1; wr[4 + wid] = s2; }
        __syncthreads();
        if (tid == 0) {
            sl1p[block]  = wr[0] + wr[1] + wr[2] + wr[3];
            bcepp[block] = wr[4] + wr[5] + wr[6] + wr[7];
        }
    }

    __threadfence();
    __syncthreads();
    if (tid == 0) shSel = atomicAdd(&rowdone[row], 1u);
    __syncthreads();
    if (shSel != BPR - 1) return;

    // ================= PHASE B: per-row top-k select =================
    __threadfence();
    const unsigned n = atomicAdd(&candcnt[row], 0u);
    const int np = (int)atomicAdd(&nprow[row], 0u);
    long long k = (long long)np * NEGPOS;
    if (k > D_) k = D_;
    long long negs = (long long)D_ - np;
    if (k > negs) k = negs;

    const float* crow = cand + (size_t)row * CAPR;
    const float* rowc = conf + row * D_;
    const int*   rowt = conft + row * D_;
    float xT = 0.0f;
    int rem = 0;
    double nsum = 0.0;

    if (k > 0) {
        const bool fb = ((long long)n < k) || (n > (unsigned)CAPR);
        if (!fb) {
            for (int i = tid; i < HBINS; i += 256) sh.b.hist[i] = 0;
            if (tid == 0) shCj = 0;
            __syncthreads();
            for (unsigned i = tid; i < n; i += 256)
                atomicAdd(&sh.b.hist[bin_of_x(crow[i])], 1u);
            __syncthreads();

            {
                unsigned s = 0; const int b0 = tid * 16;
#pragma unroll
                for (int i = 0; i < 16; i++) s += sh.b.hist[b0 + i];
                unsigned suf = s;
#pragma unroll
                for (int o = 1; o < 64; o <<= 1) {
                    unsigned v = __shfl_down(suf, o, 64);
                    if (lane + o < 64) suf += v;
                }
                if (lane == 0) wsuf[wid] = suf;
                __syncthreads();
                unsigned add = 0;
                for (int w = wid + 1; w < 4; w++) add += wsuf[w];
                suf += add;
                const unsigned sufx = suf - s;
                if ((long long)sufx < k && (long long)suf >= k) {
                    long long cum = sufx;
                    for (int b = tid * 16 + 15; b >= tid * 16; b--) {
                        cum += sh.b.hist[b];
                        if (cum >= k) {
                            shJ = (unsigned)b;
                            shRemJ = (unsigned)(k - (cum - (long long)sh.b.hist[b]));
                            break;
                        }
                    }
                }
            }
            __syncthreads();
            const unsigned J = shJ, remJ = shRemJ;

            for (unsigned i = tid; i < n; i += 256) {
                float x = crow[i];
                if ((unsigned)bin_of_x(x) == J) {
                    unsigned p = atomicAdd(&shCj, 1u);
                    if (p < CJCAP) sh.b.ubuf[p] = __float_as_uint(x);
                }
            }
            __syncthreads();
            const unsigned cj = shCj;

            if (cj <= CJCAP) {
                for (unsigned i = tid; i < cj; i += 256) {
                    const float xi = __uint_as_float(sh.b.ubuf[i]);
                    unsigned gt = 0, ge = 0;
                    for (unsigned l = 0; l < cj; l++) {
                        const float xl = __uint_as_float(sh.b.ubuf[l]);
                        gt += (xl > xi) ? 1u : 0u;
                        ge += (xl >= xi) ? 1u : 0u;
                    }
                    if (gt < remJ && ge >= remJ) shXT = xi;
                }
                __syncthreads();
                xT = shXT;
            } else {
                unsigned lo = 0u, hi = 0xFFFFFFFFu;
                for (int it = 0; it < 32; it++) {
                    const unsigned mid = lo + ((hi - lo) >> 1);
                    const float fm = unsortkey(mid);
                    int c = 0;
                    for (unsigned i = tid; i < n; i += 256)
                        if (crow[i] > fm) c++;
                    int w = wredI(c);
                    __syncthreads();
                    if (lane == 0) shI[wid] = w;
                    __syncthreads();
                    const int tot = shI[0] + shI[1] + shI[2] + shI[3];
                    if ((long long)tot >= k) lo = mid; else hi = mid;
                }
                xT = unsortkey(hi);
            }

            int c = 0;
            double acc = 0.0;
            for (unsigned i = tid; i < n; i += 256) {
                float x = crow[i];
                if (x > xT) { c++; acc += (double)softplus_f(x); }
            }
            int w = wredI(c);
            double t = wredD(acc);
            __syncthreads();
            if (lane == 0) { shI[wid] = w; wr[wid] = t; }
            __syncthreads();
            rem = (int)(k - (long long)(shI[0] + shI[1] + shI[2] + shI[3]));
            nsum = wr[0] + wr[1] + wr[2] + wr[3] +
                   (double)rem * (double)softplus_f(xT);
        } else {
            unsigned lo = 0u, hi = 0xFFFFFFFFu;
            for (int it = 0; it < 32; it++) {
                const unsigned mid = lo + ((hi - lo) >> 1);
                const float fm = unsortkey(mid);
                int c = 0;
                for (int i = tid; i < D_; i += 256)
                    if (rowt[i] <= 0 && rowc[i] > fm) c++;
                int w = wredI(c);
                __syncthreads();
                if (lane == 0) shI[wid] = w;
                __syncthreads();
                const int tot = shI[0] + shI[1] + shI[2] + shI[3];
                if ((long long)tot >= k) lo = mid; else hi = mid;
            }
            xT = unsortkey(hi);
            int c = 0;
            double acc = 0.0;
            for (int i = tid; i < D_; i += 256) {
                if (rowt[i] <= 0) {
                    float x = rowc[i];
                    if (x > xT) { c++; acc += (double)softplus_f(x); }
                }
            }
            int w = wredI(c);
            double t = wredD(acc);
            __syncthreads();
            if (lane == 0) { shI[wid] = w; wr[wid] = t; }
            __syncthreads();
            rem = (int)(k - (long long)(shI[0] + shI[1] + shI[2] + shI[3]));
            nsum = wr[0] + wr[1] + wr[2] + wr[3] +
                   (double)rem * (double)softplus_f(xT);
        }
    }

    if (tid == 0) { negsum[row] = nsum; kselp[row] = (int)k; }

    __threadfence();
    __syncthreads();
    if (tid == 0) shWin = atomicAdd(alldone, 1u);
    __syncthreads();
    if (shWin != B_ - 1) return;

    // ================= PHASE C: final combine =================
    __threadfence();
    {
        double a = 0.0, b = 0.0, c = 0.0;
        int nn = 0, kk = 0;
        for (int i = tid; i < NBLK; i += 256) { a += sl1p[i]; b += bcepp[i]; }
        if (tid < B_) {                     // tid 0..63 = wave 0 only
            nn = (int)atomicAdd(&nprow[tid], 0u);
            kk = kselp[tid];
            c = negsum[tid];
        }
        double ra = wredD(a), rb = wredD(b), rc = wredD(c);
        int rn = wredI(nn), rk = wredI(kk);
        __syncthreads();
        if (lane == 0) { wr[wid] = ra; wr[4 + wid] = rb; wrC[wid] = rc;
                         shN[wid] = rn; shK[wid] = rk; }
        __syncthreads();
        if (tid == 0) {
            double SL1 = wr[0] + wr[1] + wr[2] + wr[3];
            double BCE = wr[4] + wr[5] + wr[6] + wr[7];
            double NSUM = wrC[0] + wrC[1] + wrC[2] + wrC[3];  // waves 1-3 add 0
            double Np = (double)(shN[0] + shN[1] + shN[2] + shN[3]);
            double Kt = (double)(shK[0] + shK[1] + shK[2] + shK[3]);
            double out0 = (Np > 0.0) ? (SL1 / (4.0 * Np)) / Np : 0.0;
            double denom = Np + Kt;
            double out1 = (Np > 0.0 && denom > 0.0) ? ((BCE + NSUM) / denom) / Np : 0.0;
            out[0] = (float)out0;
            out[1] = (float)out1;
        }
    }
}

extern "C" void kernel_launch(void* const* d_in, const int* in_sizes, int n_in,
                              void* d_out, int out_size, void* d_ws, size_t ws_size,
                              hipStream_t stream)
{
    const float4* loc4  = (const float4*)d_in[0];   // (B,D,4) f32
    const float*  conf  = (const float*)d_in[1];    // (B,D,1) f32
    const float4* loct4 = (const float4*)d_in[2];   // (B,D,4) f32
    const int*    conft = (const int*)d_in[3];      // (B,D)   i32
    unsigned char* ws = (unsigned char*)d_ws;
    float* out = (float*)d_out;

    hipMemsetAsync(ws, 0, ZERO_BYTES, stream);      // counters only (1 KB)
    mbl_fused<<<dim3(NBLK), dim3(256), 0, stream>>>(loc4, conf, loct4, conft, ws, out);
}

// Round 9
// 177.657 us; speedup vs baseline: 1.8634x; 1.8634x over previous
//
#include <hip/hip_runtime.h>
#include <stdint.h>

// MultiBoxLoss: B=64 rows, D=65536 anchors, ~2% positives.
// R9: revert R8's fusion (per-block __threadfence on gfx950 = serialized L2
// writeback/invalidate, ~100ns each; 1024-block fence storm cost ~210us).
// Back to 3 launches, and ksel's ~20us attacked structurally: k1 now also
// builds a per-block 256-bin candidate histogram (plain stores, no atomics,
// no memset); ksel merges 16 histograms, finds bin J + remJ with a single
// 256-thread shfl suffix scan (1 bin/thread), then does ONE pass over the
// row's candidates (fp64 sum of bins>J + gather ~150 bin-J members) and a
// tiny rank-select. No global atomics, no fences anywhere.

#define B_ 64
#define D_ 65536
#define NEGPOS 3
#define BPR 16                 // blocks per row
#define NBLK (B_ * BPR)        // 1024
#define CHUNK (D_ / BPR)       // 4096 elements per block
#define XC 1.25f               // candidate cutoff (~10.6% of negatives)
#define HBINS 256              // histogram bins over x in [XC, XC+XRANGE)
#define XRANGE 5.0f
#define CJCAP 2048             // bin-J gather capacity (expect ~150)

// ---------------- ws layout (bytes), nothing needs zeroing ----------------
#define OFF_SL1P     0                      // double[NBLK]
#define OFF_BCEP     8192                   // double[NBLK]
#define OFF_NP       16384                  // u32[NBLK]
#define OFF_CC       20480                  // u32[NBLK]
#define OFF_NEGSUM   24576                  // double[64]
#define OFF_KSEL     25088                  // int[64]
#define OFF_BHIST    32768                  // u32[NBLK][256] = 1 MiB
#define OFF_CAND     1081344                // float[NBLK][CHUNK] = 16 MiB

__device__ __forceinline__ float softplus_f(float x) {   // bce for t=0
    return fmaxf(x, 0.0f) + log1pf(expf(-fabsf(x)));
}

__device__ __forceinline__ int bin_of_x(float x) {
    int b = (int)((x - XC) * ((float)HBINS / XRANGE));
    return max(0, min(HBINS - 1, b));
}

__device__ __forceinline__ float unsortkey(unsigned s) {
    unsigned u = (s & 0x80000000u) ? (s & 0x7FFFFFFFu) : ~s;
    return __uint_as_float(u);
}

__device__ __forceinline__ float smooth_l1_4(float4 a, float4 b) {
    float s = 0.0f, d, ad;
    d = a.x - b.x; ad = fabsf(d); s += (ad < 1.0f) ? 0.5f * d * d : ad - 0.5f;
    d = a.y - b.y; ad = fabsf(d); s += (ad < 1.0f) ? 0.5f * d * d : ad - 0.5f;
    d = a.z - b.z; ad = fabsf(d); s += (ad < 1.0f) ? 0.5f * d * d : ad - 0.5f;
    d = a.w - b.w; ad = fabsf(d); s += (ad < 1.0f) ? 0.5f * d * d : ad - 0.5f;
    return s;
}

__device__ __forceinline__ double wredD(double v) {
#pragma unroll
    for (int o = 32; o > 0; o >>= 1) v += __shfl_down(v, o, 64);
    return v;
}
__device__ __forceinline__ int wredI(int v) {
#pragma unroll
    for (int o = 32; o > 0; o >>= 1) v += __shfl_down(v, o, 64);
    return v;
}

__device__ __forceinline__ int blockSumI(int v, int* sh) {
    int w = wredI(v);
    const int lane = threadIdx.x & 63, wid = threadIdx.x >> 6;
    __syncthreads();
    if (lane == 0) sh[wid] = w;
    __syncthreads();
    return sh[0] + sh[1] + sh[2] + sh[3];
}

// K1: one coalesced pass over conf+conft per 4096-elem chunk; compacts
// candidates (x>=XC) to a private per-block segment, positives gathered
// in-block; NEW: per-block 256-bin candidate histogram (plain stores).
__global__ void __launch_bounds__(256)
mbl_k1(const float4* __restrict__ loc4, const float* __restrict__ conf,
       const float4* __restrict__ loct4, const int* __restrict__ conft,
       unsigned char* __restrict__ ws)
{
    __shared__ float lcand[CHUNK];         // 16 KB
    __shared__ unsigned short lpos[CHUNK]; // 8 KB
    __shared__ unsigned lhist[HBINS];      // 1 KB
    __shared__ unsigned wtot[4];
    __shared__ double wr[8];

    const int block = blockIdx.x;
    const int base = block * CHUNK;
    const float4* c4 = (const float4*)(conf + base);
    const int4*   t4 = (const int4*)(conft + base);
    const int lane = threadIdx.x & 63, wid = threadIdx.x >> 6;
    const int tid = threadIdx.x;

    lhist[tid] = 0;                        // 256 threads, 256 bins

    float4 xv[4]; int4 tv[4];
#pragma unroll
    for (int it = 0; it < 4; it++) {
        const int g = tid + it * 256;
        xv[it] = c4[g];
        tv[it] = t4[g];
    }
    __syncthreads();

    // pass 1: classify + count + histogram (~190 live bins -> low conflict)
    double bcep = 0.0;
    unsigned cntc = 0, cntp = 0;
#pragma unroll
    for (int it = 0; it < 4; it++) {
#pragma unroll
        for (int c = 0; c < 4; c++) {
            float x = (c == 0) ? xv[it].x : (c == 1) ? xv[it].y : (c == 2) ? xv[it].z : xv[it].w;
            int   t = (c == 0) ? tv[it].x : (c == 1) ? tv[it].y : (c == 2) ? tv[it].z : tv[it].w;
            if (t > 0) { cntp++; bcep += (double)(softplus_f(x) - x); }
            else if (x >= XC) { cntc++; atomicAdd(&lhist[bin_of_x(x)], 1u); }
        }
    }

    // packed block exclusive scan (fields <= 4096: no carry)
    unsigned pk = (cntc << 16) | cntp;
    unsigned incl = pk;
#pragma unroll
    for (int o = 1; o < 64; o <<= 1) {
        unsigned v = __shfl_up(incl, o, 64);
        if (lane >= o) incl += v;
    }
    unsigned excl = incl - pk;
    if (lane == 63) wtot[wid] = incl;
    __syncthreads();
    unsigned wbase = 0;
    for (int w = 0; w < wid; w++) wbase += wtot[w];
    const unsigned tot = wtot[0] + wtot[1] + wtot[2] + wtot[3];
    const unsigned totc = tot >> 16, totp = tot & 0xFFFFu;
    unsigned offc = (excl >> 16) + (wbase >> 16);
    unsigned offp = (excl & 0xFFFFu) + (wbase & 0xFFFFu);

    // pass 2: predicated LDS scatter at scanned offsets
#pragma unroll
    for (int it = 0; it < 4; it++) {
#pragma unroll
        for (int c = 0; c < 4; c++) {
            float x = (c == 0) ? xv[it].x : (c == 1) ? xv[it].y : (c == 2) ? xv[it].z : xv[it].w;
            int   t = (c == 0) ? tv[it].x : (c == 1) ? tv[it].y : (c == 2) ? tv[it].z : tv[it].w;
            const int li = (tid + it * 256) * 4 + c;
            if (t > 0) lpos[offp++] = (unsigned short)li;
            else if (x >= XC) lcand[offc++] = x;
        }
    }
    __syncthreads();

    // flush: candidates (coalesced) + histogram (256 plain stores)
    float* seg = (float*)(ws + OFF_CAND) + (size_t)block * CHUNK;
    for (unsigned i = tid; i < totc; i += 256) seg[i] = lcand[i];
    ((unsigned*)(ws + OFF_BHIST))[(size_t)block * HBINS + tid] = lhist[tid];

    // batched positive gather (~20 per block, independent)
    double sl1 = 0.0;
    for (unsigned i = tid; i < totp; i += 256) {
        const int e = base + (int)lpos[i];
        sl1 += (double)smooth_l1_4(loc4[e], loct4[e]);
    }

    double s1 = wredD(sl1), s2 = wredD(bcep);
    if (lane == 0) { wr[wid] = s1; wr[4 + wid] = s2; }
    __syncthreads();
    if (tid == 0) {
        ((double*)(ws + OFF_SL1P))[block] = wr[0] + wr[1] + wr[2] + wr[3];
        ((double*)(ws + OFF_BCEP))[block] = wr[4] + wr[5] + wr[6] + wr[7];
        ((unsigned*)(ws + OFF_NP))[block] = totp;
        ((unsigned*)(ws + OFF_CC))[block] = totc;
    }
}

// Ksel: one block per row. Merge 16 histograms -> suffix scan (1 bin/thread)
// -> one candidate pass (sum bins>J, gather bin J) -> rank select -> done.
__global__ void __launch_bounds__(256)
mbl_ksel(const float* __restrict__ conf, const int* __restrict__ conft,
         unsigned char* __restrict__ ws)
{
    __shared__ unsigned segoff[BPR + 1], scc[BPR];
    __shared__ unsigned wsuf[4];
    __shared__ unsigned ubuf[CJCAP];       // 8 KB
    __shared__ unsigned shJ, shRemJ, shCj, shNP;
    __shared__ float shXT;
    __shared__ int shI[4];
    __shared__ double wr[4];

    const int row = blockIdx.x;
    const int tid = threadIdx.x, lane = tid & 63, wid = tid >> 6;
    const unsigned* cc  = (const unsigned*)(ws + OFF_CC) + row * BPR;
    const unsigned* npb = (const unsigned*)(ws + OFF_NP) + row * BPR;

    // wave-0: prefix scan of 16 segment counts + np total
    if (wid == 0) {
        unsigned c = (lane < BPR) ? cc[lane] : 0u;
        unsigned p = (lane < BPR) ? npb[lane] : 0u;
        unsigned inc = c;
#pragma unroll
        for (int o = 1; o < BPR; o <<= 1) {
            unsigned v = __shfl_up(inc, o, 64);
            if (lane >= o) inc += v;
        }
        unsigned ptot = p;
#pragma unroll
        for (int o = 1; o < BPR; o <<= 1) ptot += __shfl_down(ptot, o, 64);
        if (lane < BPR) { segoff[lane] = inc - c; scc[lane] = c; }
        if (lane == BPR - 1) segoff[BPR] = inc;
        if (lane == 0) { shNP = ptot; shCj = 0; shJ = 0xFFFFFFFFu; }
    }
    __syncthreads();

    const int np = (int)shNP;
    const unsigned n = segoff[BPR];
    long long k = (long long)np * NEGPOS;
    if (k > D_) k = D_;
    long long negs = (long long)D_ - np;
    if (k > negs) k = negs;
    if (tid == 0) ((int*)(ws + OFF_KSEL))[row] = (int)k;
    if (k <= 0) {
        if (tid == 0) ((double*)(ws + OFF_NEGSUM))[row] = 0.0;
        return;
    }

    const float* cand = (const float*)(ws + OFF_CAND);
    const float* rowc = conf + row * D_;
    const int*   rowt = conft + row * D_;
    float xT = 0.0f;
    int c = 0;
    double acc = 0.0;

    if ((long long)n >= k) {
        // merge 16 per-block histograms: bin 'tid' summed across blocks
        const unsigned* bh = (const unsigned*)(ws + OFF_BHIST) +
                             (size_t)(row * BPR) * HBINS;
        unsigned h = 0;
#pragma unroll
        for (int s = 0; s < BPR; s++) h += bh[s * HBINS + tid];

        // block-wide inclusive suffix scan (1 bin per thread)
        unsigned suf = h;
#pragma unroll
        for (int o = 1; o < 64; o <<= 1) {
            unsigned v = __shfl_down(suf, o, 64);
            if (lane + o < 64) suf += v;
        }
        if (lane == 0) wsuf[wid] = suf;
        __syncthreads();
        unsigned add = 0;
        for (int w = wid + 1; w < 4; w++) add += wsuf[w];
        suf += add;
        if ((long long)suf >= k && (long long)(suf - h) < k) {
            shJ = (unsigned)tid;                       // exactly one thread
            shRemJ = (unsigned)(k - (long long)(suf - h));
        }
        __syncthreads();
        const unsigned J = shJ, remJ = shRemJ;

        // ONE pass over candidates: fp64 sum of bins>J + gather bin-J
        {
            const int s = tid >> 4, li = tid & 15;
            const float* gseg = cand + (size_t)(row * BPR + s) * CHUNK;
            const unsigned cs = scc[s];
            for (unsigned i = li; i < cs; i += 16) {
                float x = gseg[i];
                unsigned b = (unsigned)bin_of_x(x);
                if (b > J) { c++; acc += (double)softplus_f(x); }
                else if (b == J) {
                    unsigned p = atomicAdd(&shCj, 1u);
                    if (p < CJCAP) ubuf[p] = __float_as_uint(x);
                }
            }
        }
        __syncthreads();
        const unsigned cj = shCj;

        if (cj <= (unsigned)CJCAP) {
            // rank-select the remJ-th largest VALUE in bin J (~150 elems;
            // equal values all write the same bits -> benign race)
            for (unsigned i = tid; i < cj; i += 256) {
                const float xi = __uint_as_float(ubuf[i]);
                unsigned gt = 0, ge = 0;
                for (unsigned l = 0; l < cj; l++) {
                    const float xl = __uint_as_float(ubuf[l]);
                    gt += (xl > xi) ? 1u : 0u;
                    ge += (xl >= xi) ? 1u : 0u;
                }
                if (gt < remJ && ge >= remJ) shXT = xi;
            }
            __syncthreads();
            xT = shXT;
            for (unsigned i = tid; i < cj; i += 256) {
                const float xi = __uint_as_float(ubuf[i]);
                if (xi > xT) { c++; acc += (double)softplus_f(xi); }
            }
        } else {
            // pathological mass-tie in one bin: exact uint bisect over crow
            const int s = tid >> 4, li = tid & 15;
            const float* gseg = cand + (size_t)(row * BPR + s) * CHUNK;
            const unsigned cs = scc[s];
            unsigned lo = 0u, hi = 0xFFFFFFFFu;
            for (int it = 0; it < 32; it++) {
                const unsigned mid = lo + ((hi - lo) >> 1);
                const float fm = unsortkey(mid);
                int c2 = 0;
                for (unsigned i = li; i < cs; i += 16)
                    if (gseg[i] > fm) c2++;
                const int tot = blockSumI(c2, shI);
                if ((long long)tot >= k) lo = mid; else hi = mid;
            }
            xT = unsortkey(hi);
            c = 0; acc = 0.0;
            for (unsigned i = li; i < cs; i += 16) {
                float x = gseg[i];
                if (x > xT) { c++; acc += (double)softplus_f(x); }
            }
        }
    } else {
        // exactness fallback (n < k, never on this data): full-row bisect
        unsigned lo = 0u, hi = 0xFFFFFFFFu;
        for (int it = 0; it < 32; it++) {
            const unsigned mid = lo + ((hi - lo) >> 1);
            const float fm = unsortkey(mid);
            int c2 = 0;
            for (int i = tid; i < D_; i += 256)
                if (rowt[i] <= 0 && rowc[i] > fm) c2++;
            const int tot = blockSumI(c2, shI);
            if ((long long)tot >= k) lo = mid; else hi = mid;
        }
        xT = unsortkey(hi);
        c = 0; acc = 0.0;
        for (int i = tid; i < D_; i += 256) {
            if (rowt[i] <= 0) {
                float x = rowc[i];
                if (x > xT) { c++; acc += (double)softplus_f(x); }
            }
        }
    }

    // common tail: rem + exact fp64 sum
    int w = wredI(c);
    double t = wredD(acc);
    __syncthreads();
    if (lane == 0) { shI[wid] = w; wr[wid] = t; }
    __syncthreads();
    if (tid == 0) {
        const int tot = shI[0] + shI[1] + shI[2] + shI[3];
        const int rem = (int)(k - (long long)tot);
        ((double*)(ws + OFF_NEGSUM))[row] =
            wr[0] + wr[1] + wr[2] + wr[3] +
            (double)rem * (double)softplus_f(xT);
    }
}

// K5: reduce per-block partials -> two output scalars.
__global__ void __launch_bounds__(256)
mbl_k5(unsigned char* __restrict__ ws, float* __restrict__ out)
{
    __shared__ double wrA[4], wrB[4], wrC[4];
    __shared__ int shN[4], shK[4];
    const double* sl1p = (const double*)(ws + OFF_SL1P);
    const double* bcep = (const double*)(ws + OFF_BCEP);
    const unsigned* npb = (const unsigned*)(ws + OFF_NP);
    const int* ksel = (const int*)(ws + OFF_KSEL);
    const double* ns = (const double*)(ws + OFF_NEGSUM);

    double a = 0.0, b = 0.0, c = 0.0;
    int n = 0, kk = 0;
    for (int i = threadIdx.x; i < NBLK; i += 256) {
        a += sl1p[i]; b += bcep[i]; n += (int)npb[i];
    }
    if (threadIdx.x < 64) { kk = ksel[threadIdx.x]; c = ns[threadIdx.x]; }

    double ra = wredD(a), rb = wredD(b), rc = wredD(c);
    int rn = wredI(n), rk = wredI(kk);
    const int lane = threadIdx.x & 63, wid = threadIdx.x >> 6;
    if (lane == 0) { wrA[wid] = ra; wrB[wid] = rb; wrC[wid] = rc; shN[wid] = rn; shK[wid] = rk; }
    __syncthreads();
    if (threadIdx.x == 0) {
        double SL1 = wrA[0] + wrA[1] + wrA[2] + wrA[3];
        double BCE = wrB[0] + wrB[1] + wrB[2] + wrB[3];
        double NSUM = wrC[0] + wrC[1] + wrC[2] + wrC[3];
        double Np = (double)(shN[0] + shN[1] + shN[2] + shN[3]);
        double Kt = (double)(shK[0] + shK[1] + shK[2] + shK[3]);
        double out0 = (Np > 0.0) ? (SL1 / (4.0 * Np)) / Np : 0.0;
        double denom = Np + Kt;
        double out1 = (Np > 0.0 && denom > 0.0) ? ((BCE + NSUM) / denom) / Np : 0.0;
        out[0] = (float)out0;
        out[1] = (float)out1;
    }
}

extern "C" void kernel_launch(void* const* d_in, const int* in_sizes, int n_in,
                              void* d_out, int out_size, void* d_ws, size_t ws_size,
                              hipStream_t stream)
{
    const float4* loc4  = (const float4*)d_in[0];   // (B,D,4) f32
    const float*  conf  = (const float*)d_in[1];    // (B,D,1) f32
    const float4* loct4 = (const float4*)d_in[2];   // (B,D,4) f32
    const int*    conft = (const int*)d_in[3];      // (B,D)   i32
    unsigned char* ws = (unsigned char*)d_ws;
    float* out = (float*)d_out;

    mbl_k1<<<dim3(NBLK), dim3(256), 0, stream>>>(loc4, conf, loct4, conft, ws);
    mbl_ksel<<<dim3(B_), dim3(256), 0, stream>>>(conf, conft, ws);
    mbl_k5<<<dim3(1), dim3(256), 0, stream>>>(ws, out);
}